// Round 5
// baseline (305.972 us; speedup 1.0000x reference)
//
#include <hip/hip_runtime.h>
#include <math.h>

// Problem constants
constexpr int B_ = 4, C_ = 256, H4 = 96, W4 = 320, HF = 384, WF = 1280;
constexpr int CHUNKS = 5;              // 320 / 64 px per block
constexpr float EPSV = 1e-6f;
constexpr int LOW = B_ * H4 * W4;      // 122880
constexpr int FULL = B_ * HF * WF;     // 1966080

// Phase 1: banded cosine correlation + softmax + downsampled disp -> dref, conf.
// Round-5 structure: concurrency from WAVE COUNT, not per-wave pipelining.
//   - pixel-per-lane (64 px/wave), wave w owns channels [64w, 64w+64)
//   - per channel: 8 scalar loads (fL[x], fR[x-3..x+3]); the 7 tap loads hit
//     the same 2-3 cache lines per wave -> L1 absorbs redundancy, unique
//     HBM/L2 traffic unchanged
//   - NO LDS, NO barriers, NO explicit waitcnt in the hot loop; depth-1
//     register prefetch only (register pressure ~55 -> no collapse motive)
//   - per-lane state: 12 accumulators -> VGPR ~60 -> 6-8 waves/SIMD resident,
//     3-5x round-0's residency; 24-32 independent wave-streams/CU supply the
//     outstanding misses that Little's law needs for streaming BW
// Halo norms are free: lane 0's taps 0..2 ARE pixels x0-3..x0-1; lane 63's
// taps 4..6 are x0+64..x0+66 (circular wrap, jnp.roll).
__global__ __launch_bounds__(256, 6)
void phase1(const float* __restrict__ fL, const float* __restrict__ fR,
            const float* __restrict__ D, float* __restrict__ dref,
            float* __restrict__ conf)
{
    const int bi = blockIdx.x;
    const int chunk = bi % CHUNKS;
    const int y = (bi / CHUNKS) % H4;
    const int b = bi / (CHUNKS * H4);
    const int tid = threadIdx.x;
    const int wave = tid >> 6;
    const int lane = tid & 63;
    const int x0 = chunk * 64;
    const int x = x0 + lane;

    const size_t chanStride = (size_t)H4 * W4;                 // 30720
    const size_t rowBase = (((size_t)b * C_) * H4 + y) * W4;

    const float* pL = fL + rowBase + (size_t)(wave * 64) * chanStride;
    const float* pR = fR + rowBase + (size_t)(wave * 64) * chanStride;

    // 7 tap indices with circular wrap (only lanes 0-2 / 61-63 ever wrap).
    int xk[7];
#pragma unroll
    for (int k = 0; k < 7; ++k) {
        int t = x + k - 3;
        if (t < 0) t += W4; else if (t >= W4) t -= W4;
        xk[k] = t;
    }

    float dot[7] = {0.f,0.f,0.f,0.f,0.f,0.f,0.f};
    float ssL = 0.f, ssR = 0.f;
    float sH[3] = {0.f, 0.f, 0.f};
    const bool rsel = (lane == 63);    // right-edge lane accumulates right halo

    // Depth-1 prefetch: channel 0.
    float a0 = pL[x];
    float w0[7];
#pragma unroll
    for (int k = 0; k < 7; ++k) w0[k] = pR[xk[k]];

#pragma unroll 2
    for (int c = 0; c < 64; ++c) {     // 64 channels per wave
        float a1 = 0.f;
        float w1[7];
        if (c < 63) {                  // prefetch next channel
            const float* qL = pL + (size_t)(c + 1) * chanStride;
            const float* qR = pR + (size_t)(c + 1) * chanStride;
            a1 = qL[x];
#pragma unroll
            for (int k = 0; k < 7; ++k) w1[k] = qR[xk[k]];
        }
        // consume current channel
#pragma unroll
        for (int k = 0; k < 7; ++k) dot[k] = fmaf(a0, w0[k], dot[k]);
        ssL = fmaf(a0, a0, ssL);
        ssR = fmaf(w0[3], w0[3], ssR);         // w0[3] == fR[x]
#pragma unroll
        for (int j = 0; j < 3; ++j) {          // halo norms (lanes 0 / 63 only meaningful)
            const float t = rsel ? w0[4 + j] : w0[j];
            sH[j] = fmaf(t, t, sH[j]);
        }
        // rotate
        a0 = a1;
#pragma unroll
        for (int k = 0; k < 7; ++k) w0[k] = w1[k];
    }

    // Cross-wave reduction (one-time epilogue; only sync points in the kernel).
    __shared__ float part[256][13];    // 0-6 dot, 7 ssL, 8 ssR, 9-11 sH; pad 13
    __shared__ float sss[70];          // squared fR norms for pixels x0-3..x0+66
#pragma unroll
    for (int k = 0; k < 7; ++k) part[tid][k] = dot[k];
    part[tid][7] = ssL;
    part[tid][8] = ssR;
#pragma unroll
    for (int j = 0; j < 3; ++j) part[tid][9 + j] = sH[j];
    __syncthreads();

    float rdot[7], rsL = 0.f;
    if (tid < 64) {
#pragma unroll
        for (int k = 0; k < 7; ++k)
            rdot[k] = part[tid][k] + part[tid + 64][k]
                    + part[tid + 128][k] + part[tid + 192][k];
        rsL = part[tid][7] + part[tid + 64][7] + part[tid + 128][7] + part[tid + 192][7];
        const float rsR = part[tid][8] + part[tid + 64][8]
                        + part[tid + 128][8] + part[tid + 192][8];
        sss[3 + tid] = rsR;
        if (tid < 3)                   // left halo px x0-3+tid, from lane 0 of each wave
            sss[tid] = part[0][9 + tid] + part[64][9 + tid]
                     + part[128][9 + tid] + part[192][9 + tid];
        if (tid >= 61) {               // right halo px x0+64+j, from lane 63 of each wave
            const int j = tid - 61;
            sss[67 + j] = part[63][9 + j] + part[127][9 + j]
                        + part[191][9 + j] + part[255][9 + j];
        }
    }
    __syncthreads();

    if (tid < 64) {
        const float nLv = fmaxf(sqrtf(rsL), EPSV);
        float cost[7];
#pragma unroll
        for (int k = 0; k < 7; ++k) {
            // k indexes neighbor x+(k-3); reference cost[i] (d=i-3) uses x+(3-i)
            const float nR = fmaxf(sqrtf(sss[tid + k]), EPSV);
            cost[6 - k] = (rdot[k] / (nLv * nR)) * 10.0f;   // /TEMP, TEMP=0.1
        }
        float m = cost[0];
#pragma unroll
        for (int i = 1; i < 7; ++i) m = fmaxf(m, cost[i]);
        float sum = 0.f, dsum = 0.f;
#pragma unroll
        for (int i = 0; i < 7; ++i) {
            const float e = __expf(cost[i] - m);
            sum += e;
            dsum += e * (float)(i - 3);
        }
        const float delta = dsum / sum;
        const float cf = 1.0f / sum;               // max p = exp(0)/sum

        // Exact 4x downsample of disp_full: y0=4y+1,y1=4y+2, wy=wx=0.5 -> mean 2x2, /4
        const int xpix = x0 + tid;
        const int Y0 = 4 * y + 1, X0 = 4 * xpix + 1;
        const size_t dbase = ((size_t)b * HF + Y0) * WF + X0;
        const float s4 = D[dbase] + D[dbase + 1] + D[dbase + WF] + D[dbase + WF + 1];
        const float disp0 = s4 * 0.0625f;          // (sum/4)/4

        const size_t o = ((size_t)b * H4 + y) * W4 + xpix;
        dref[o] = disp0 + delta;
        conf[o] = cf;
    }
}

// dq = dref - 0.2 * Laplacian(dref) computed on the fly (zero padding)
__device__ __forceinline__ float dq_val(const float* __restrict__ dref,
                                        size_t base, int yq, int xq)
{
    size_t i = base + (size_t)yq * W4 + xq;
    float c  = dref[i];
    float up = (yq > 0)      ? dref[i - W4] : 0.f;
    float dn = (yq < H4 - 1) ? dref[i + W4] : 0.f;
    float lf = (xq > 0)      ? dref[i - 1]  : 0.f;
    float rt = (xq < W4 - 1) ? dref[i + 1]  : 0.f;
    return c - 0.2f * (up + dn + lf + rt - 4.f * c);
}

// Phase 2: 4x bilinear upsample of dq (*4) and conf; 4 outputs per thread.
__global__ void phase2(const float* __restrict__ dref, const float* __restrict__ cf,
                       float* __restrict__ out)
{
    const int idx = blockIdx.x * blockDim.x + threadIdx.x;
    constexpr int WQ = WF / 4;                 // 320 quads per row
    if (idx >= FULL / 4) return;
    const int k = idx % WQ;
    const int Y = (idx / WQ) % HF;
    const int b = idx / (WQ * HF);

    const float ys = fmaxf((Y + 0.5f) * 0.25f - 0.5f, 0.f);
    const float y0f = floorf(ys);
    const float wy = ys - y0f;
    const int y0 = min((int)y0f, H4 - 1);
    const int y1 = min(y0 + 1, H4 - 1);
    const size_t base = (size_t)b * (H4 * W4);

    const int xa = max(k - 1, 0);
    const int xb = k;
    const int xc = min(k + 1, W4 - 1);

    const float da = (1.f - wy) * dq_val(dref, base, y0, xa) + wy * dq_val(dref, base, y1, xa);
    const float db = (1.f - wy) * dq_val(dref, base, y0, xb) + wy * dq_val(dref, base, y1, xb);
    const float dc = (1.f - wy) * dq_val(dref, base, y0, xc) + wy * dq_val(dref, base, y1, xc);

    const size_t r0 = base + (size_t)y0 * W4;
    const size_t r1 = base + (size_t)y1 * W4;
    const float ca = (1.f - wy) * cf[r0 + xa] + wy * cf[r1 + xa];
    const float cb = (1.f - wy) * cf[r0 + xb] + wy * cf[r1 + xb];
    const float cc = (1.f - wy) * cf[r0 + xc] + wy * cf[r1 + xc];

    // r=0: x0=k-1 wx=0.625; r=1: x0=k-1 wx=0.875; r=2: x0=k wx=0.125; r=3: x0=k wx=0.375
    float4 dv, cv;
    dv.x = 4.0f * (0.375f * da + 0.625f * db);
    dv.y = 4.0f * (0.125f * da + 0.875f * db);
    dv.z = 4.0f * (0.875f * db + 0.125f * dc);
    dv.w = 4.0f * (0.625f * db + 0.375f * dc);
    cv.x = 0.375f * ca + 0.625f * cb;
    cv.y = 0.125f * ca + 0.875f * cb;
    cv.z = 0.875f * cb + 0.125f * cc;
    cv.w = 0.625f * cb + 0.375f * cc;

    const size_t o = (((size_t)b * HF + Y) * WF) + 4 * k;
    *(float4*)&out[o] = dv;
    *(float4*)&out[(size_t)FULL + o] = cv;
}

extern "C" void kernel_launch(void* const* d_in, const int* in_sizes, int n_in,
                              void* d_out, int out_size, void* d_ws, size_t ws_size,
                              hipStream_t stream)
{
    const float* fL = (const float*)d_in[0];
    const float* fR = (const float*)d_in[1];
    const float* D  = (const float*)d_in[2];
    float* out  = (float*)d_out;
    float* ws   = (float*)d_ws;
    float* dref = ws;
    float* conf = ws + LOW;

    phase1<<<B_ * H4 * CHUNKS, 256, 0, stream>>>(fL, fR, D, dref, conf);
    phase2<<<(FULL / 4 + 255) / 256, 256, 0, stream>>>(dref, conf, out);
}